// Round 1
// baseline (505.682 us; speedup 1.0000x reference)
//
#include <hip/hip_runtime.h>
#include <hip/hip_bf16.h>
#include <math.h>

// Problem constants (S, B, D_IN, D_SRC, D_ALIGN = 2048, 64, 512, 512, 512)
#define S_LEN 2048
#define BATCH 64
#define DDIM 512

typedef __attribute__((ext_vector_type(8))) short bf16x8;
typedef __attribute__((ext_vector_type(4))) float f32x4;
typedef __attribute__((ext_vector_type(4))) unsigned int u32x4;

typedef __attribute__((address_space(1))) const void g_void;
typedef __attribute__((address_space(3))) void l_void;

__device__ __forceinline__ unsigned short f2bf(float f) {
  unsigned int u = __float_as_uint(f);
  u += 0x7fffu + ((u >> 16) & 1u);
  return (unsigned short)(u >> 16);
}

__device__ __forceinline__ float tanh_fast(float x) {
  // tanh(x) = 1 - 2/(exp2(2*log2e*x)+1)
  float e = __builtin_amdgcn_exp2f(x * 2.88539008177793f);
  return 1.0f - 2.0f * __builtin_amdgcn_rcpf(e + 1.0f);
}

// pack two f32 into bf16x2 (lo=a, hi=b), round-half-up (matches prior kernel)
__device__ __forceinline__ unsigned pkbf(float a, float b) {
  unsigned ua = __float_as_uint(a) + 0x8000u;
  unsigned ub = __float_as_uint(b) + 0x8000u;
  return __builtin_amdgcn_perm(ub, ua, 0x07060302u);
}

// ---------------------------------------------------------------------------
// prep: W1b[a][d] = bf16(W1[a][512+d]);  uprime[b][a] = b1[a] + W1[a,:512].input[b]
// ---------------------------------------------------------------------------
__global__ __launch_bounds__(256) void prep_kernel(
    const float* __restrict__ W1, const float* __restrict__ b1,
    const float* __restrict__ input, unsigned short* __restrict__ W1b,
    float* __restrict__ uprime) {
  __shared__ float w1row[1024];
  const int a = blockIdx.x;
  const int t = threadIdx.x;
  float4 v = *(const float4*)(W1 + a * 1024 + t * 4);
  *(float4*)(w1row + t * 4) = v;
  if (t >= 128) {
    ushort4 u;
    u.x = f2bf(v.x); u.y = f2bf(v.y); u.z = f2bf(v.z); u.w = f2bf(v.w);
    *(ushort4*)(W1b + a * 512 + (t * 4 - 512)) = u;
  }
  __syncthreads();
  if (t < BATCH) {
    const float4* inp = (const float4*)(input + t * 512);
    const float4* wr = (const float4*)w1row;
    float acc = b1[a];
#pragma unroll 4
    for (int d = 0; d < 128; ++d) {
      float4 x = inp[d], w = wr[d];
      acc += x.x * w.x + x.y * w.y + x.z * w.z + x.w * w.w;
    }
    uprime[t * 512 + a] = acc;  // [b][a]
  }
}

// ---------------------------------------------------------------------------
// scores v5: BM=128 (2 s per block, grid 1024). 512 thr / 8 waves.
// Wave w owns cols w*64..w*64+63 over all 128 rows -> acc[8][4] (128 VGPR).
// B (W1b 512x64) double-buffered via GLL issued BEFORE compute (prefetch);
// A (src f32 -> bf16 128x64) reg-staged: global loads at iter top, convert +
// ds_write between the two barriers (T14 split). LDS 144.5 KB, 1 block/CU.
// XOR-chunk swizzle as before (phys 16B-chunk p = logical c ^ (row&7)):
// every ds op is at the 32-bank floor. W1b L2 traffic halved vs v4.
// Epilogue: tanh + W2 dot, LDS reduce, write scores_t[b][s] (transposed).
// ---------------------------------------------------------------------------
__global__ __launch_bounds__(512, 2) void scores_kernel(
    const float* __restrict__ src, const unsigned short* __restrict__ W1b,
    const float* __restrict__ uprime, const float* __restrict__ W2,
    float* __restrict__ scores_t) {
  __shared__ unsigned short A_sm[128 * 64];      // 16 KB
  __shared__ unsigned short B_sm[2 * 512 * 64];  // 128 KB (double-buffered)
  __shared__ float s_lds[128];

  const int t = threadIdx.x;
  const int sblk = blockIdx.x;  // 2 s per block
  const int w = t >> 6;         // wave 0..7 (uniform)
  const int lane = t & 63;
  const int quad = lane >> 4;
  const int l15 = lane & 15;

  if (t < 128) s_lds[t] = 0.f;

  f32x4 acc[8][4];
#pragma unroll
  for (int i = 0; i < 8; ++i)
#pragma unroll
    for (int j = 0; j < 4; ++j) acc[i][j] = (f32x4){0.f, 0.f, 0.f, 0.f};

  // A staging: rows of A = 128 contiguous src rows (2 s x 64 b).
  // thread t -> row ar=t>>2, quarter aq=t&3 (16 f32 = 2 bf16 16B-chunks).
  const int ar = t >> 2, aq = t & 3;
  const float* gA = src + (size_t)(sblk * 128) * DDIM + ar * DDIM + aq * 16;
  const int p0 = (2 * aq) ^ (ar & 7);  // phys chunks for logical 2aq, 2aq+1
  const int p1 = (2 * aq + 1) ^ (ar & 7);
  unsigned short* ldsA0 = A_sm + ar * 64 + p0 * 8;
  unsigned short* ldsA1 = A_sm + ar * 64 + p1 * 8;

  // B staging lane-invariant part: row-in-group br=lane>>3, phys bp=lane&7
  const int br = lane >> 3, bp = lane & 7, bc = bp ^ (br & 7);
  const unsigned short* gBl = W1b + br * DDIM + bc * 8;

  // ---- prologue: stage tile 0 (A regs -> LDS, B via GLL into buf0) ----
  {
    float4 as0 = ((const float4*)gA)[0];
    float4 as1 = ((const float4*)gA)[1];
    float4 as2 = ((const float4*)gA)[2];
    float4 as3 = ((const float4*)gA)[3];
#pragma unroll
    for (int g = 0; g < 8; ++g) {
      const unsigned short* gp = gBl + (g * 64 + w * 8) * DDIM;
      unsigned short* lp = B_sm + (g * 64 + w * 8) * 64;  // wave-uniform
      __builtin_amdgcn_global_load_lds((g_void*)gp, (l_void*)lp, 16, 0, 0);
    }
    u32x4 o0, o1;
    o0.x = pkbf(as0.x, as0.y); o0.y = pkbf(as0.z, as0.w);
    o0.z = pkbf(as1.x, as1.y); o0.w = pkbf(as1.z, as1.w);
    o1.x = pkbf(as2.x, as2.y); o1.y = pkbf(as2.z, as2.w);
    o1.z = pkbf(as3.x, as3.y); o1.w = pkbf(as3.z, as3.w);
    *(u32x4*)ldsA0 = o0;
    *(u32x4*)ldsA1 = o1;
  }
  __syncthreads();

  // ---- main loop: 8 K-steps of 64 ----
  for (int kt = 0; kt < 8; ++kt) {
    const int cur = kt & 1;
    const int pf = kt < 7;
    float4 as0, as1, as2, as3;
    if (pf) {
      // issue next A (regs) FIRST, then next B (GLL) -> compiler's wait for
      // the A-regs is a counted vmcnt that leaves the GLLs in flight.
      const float4* gAn = (const float4*)(gA + (kt + 1) * 64);
      as0 = gAn[0]; as1 = gAn[1]; as2 = gAn[2]; as3 = gAn[3];
#pragma unroll
      for (int g = 0; g < 8; ++g) {
        const unsigned short* gp = gBl + (g * 64 + w * 8) * DDIM + (kt + 1) * 64;
        unsigned short* lp =
            B_sm + (cur ^ 1) * (512 * 64) + (g * 64 + w * 8) * 64;
        __builtin_amdgcn_global_load_lds((g_void*)gp, (l_void*)lp, 16, 0, 0);
      }
    }

    // ---- compute from A_sm (current) and B buf[cur] ----
    const unsigned short* Bc = B_sm + cur * (512 * 64);
#pragma unroll
    for (int ks = 0; ks < 2; ++ks) {
      const int c = ks * 4 + quad;  // logical 16B chunk within BK=64
      bf16x8 af[8], bfr[4];
#pragma unroll
      for (int i = 0; i < 8; ++i) {
        const int r = i * 16 + l15;
        af[i] = *(const bf16x8*)(A_sm + r * 64 + ((c ^ (r & 7)) << 3));
      }
#pragma unroll
      for (int j = 0; j < 4; ++j) {
        const int n = w * 64 + j * 16 + l15;
        bfr[j] = *(const bf16x8*)(Bc + n * 64 + ((c ^ (n & 7)) << 3));
      }
#pragma unroll
      for (int i = 0; i < 8; ++i)
#pragma unroll
        for (int j = 0; j < 4; ++j)
          acc[i][j] = __builtin_amdgcn_mfma_f32_16x16x32_bf16(af[i], bfr[j],
                                                              acc[i][j], 0, 0, 0);
    }
    __syncthreads();  // all waves done reading A_sm; drains GLL (buf ready)

    if (pf) {
      u32x4 o0, o1;
      o0.x = pkbf(as0.x, as0.y); o0.y = pkbf(as0.z, as0.w);
      o0.z = pkbf(as1.x, as1.y); o0.w = pkbf(as1.z, as1.w);
      o1.x = pkbf(as2.x, as2.y); o1.y = pkbf(as2.z, as2.w);
      o1.z = pkbf(as3.x, as3.y); o1.w = pkbf(as3.z, as3.w);
      *(u32x4*)ldsA0 = o0;
      *(u32x4*)ldsA1 = o1;
    }
    __syncthreads();  // A_sm(t+1) visible to all
  }

  // ---- epilogue: tanh + W2 partial dot over this wave's 64 cols ----
  float w2r[4];
#pragma unroll
  for (int j = 0; j < 4; ++j) w2r[j] = W2[w * 64 + j * 16 + l15];

#pragma unroll
  for (int i = 0; i < 8; ++i) {
#pragma unroll
    for (int r = 0; r < 4; ++r) {
      const int row = i * 16 + quad * 4 + r;  // 0..127
      const int b = row & 63;
      const int sl = row >> 6;
      const float* up = uprime + b * 512 + w * 64 + l15;
      float sp = 0.f;
#pragma unroll
      for (int j = 0; j < 4; ++j)
        sp += w2r[j] * tanh_fast(acc[i][j][r] + up[j * 16]);
      sp += __shfl_xor(sp, 1);
      sp += __shfl_xor(sp, 2);
      sp += __shfl_xor(sp, 4);
      sp += __shfl_xor(sp, 8);
      if (l15 == 0) atomicAdd(&s_lds[sl * 64 + b], sp);
    }
  }
  __syncthreads();
  if (t < 128)  // transposed [b][s]
    scores_t[(t & 63) * S_LEN + sblk * 2 + (t >> 6)] = s_lds[t];
}

// ---------------------------------------------------------------------------
// softmax over s per b; reads contiguous scores_t[b][s]. Writes attn[s][b]
// (output) and optionally attn_t[b][s] (ws, contiguous for ctx).
// ---------------------------------------------------------------------------
__global__ __launch_bounds__(256) void softmax_kernel(
    const float* __restrict__ scores_t, const unsigned char* __restrict__ mask,
    float* __restrict__ attn_g, float* __restrict__ attn_t, int write_t) {
  __shared__ float red[256];
  const int b = blockIdx.x, t = threadIdx.x;
  float m = -__builtin_inff();
  float sc[8];
#pragma unroll
  for (int c = 0; c < 8; ++c) {
    const int s = t + c * 256;
    sc[c] = mask[s * BATCH + b] ? -__builtin_inff() : scores_t[b * S_LEN + s];
    m = fmaxf(m, sc[c]);
  }
  red[t] = m;
  __syncthreads();
  for (int off = 128; off; off >>= 1) {
    if (t < off) red[t] = fmaxf(red[t], red[t + off]);
    __syncthreads();
  }
  m = red[0];
  __syncthreads();
  float sum = 0.f;
#pragma unroll
  for (int c = 0; c < 8; ++c) sum += __expf(sc[c] - m);
  red[t] = sum;
  __syncthreads();
  for (int off = 128; off; off >>= 1) {
    if (t < off) red[t] += red[t + off];
    __syncthreads();
  }
  const float inv = 1.f / red[0];
#pragma unroll
  for (int c = 0; c < 8; ++c) {
    const int s = t + c * 256;
    const float p = __expf(sc[c] - m) * inv;
    attn_g[s * BATCH + b] = p;
    if (write_t) attn_t[b * S_LEN + s] = p;
  }
}

// ---------------------------------------------------------------------------
// ctx two-stage (no atomics). Stage 1: grid (32 s-chunks, 64 b), each block
// computes two 32-s half-partials (float4 stores, coalesced).
// ---------------------------------------------------------------------------
__global__ __launch_bounds__(256) void ctx_partial_kernel(
    const float* __restrict__ src, const float* __restrict__ attn_t,
    float* __restrict__ partial) {
  __shared__ float a_lds[64];
  const int c = blockIdx.x;  // 0..31
  const int b = blockIdx.y;  // 0..63
  const int t = threadIdx.x;
  if (t < 64) a_lds[t] = attn_t[b * S_LEN + c * 64 + t];
  __syncthreads();
  const int f4i = t & 127;
  const int sh = t >> 7;
  const float4* base =
      (const float4*)src + ((size_t)(c * 64 + sh * 32) * BATCH + b) * 128 + f4i;
  float4 acc = {0.f, 0.f, 0.f, 0.f};
#pragma unroll 8
  for (int i = 0; i < 32; ++i) {
    const float a = a_lds[sh * 32 + i];
    float4 v = base[(size_t)i * BATCH * 128];
    acc.x += a * v.x; acc.y += a * v.y; acc.z += a * v.z; acc.w += a * v.w;
  }
  ((float4*)partial)[((size_t)(c * 2 + sh) * BATCH + b) * 128 + f4i] = acc;
}

// Stage 2: ctx[b][d] = sum over 64 half-partials. grid 64, 256 thr (float2/thr).
__global__ __launch_bounds__(256) void ctx_reduce_kernel(
    const float* __restrict__ partial, float* __restrict__ ctx) {
  const int b = blockIdx.x, t = threadIdx.x;
  const float2* p = (const float2*)partial + (size_t)b * 256 + t;
  float2 acc = {0.f, 0.f};
#pragma unroll 8
  for (int c2 = 0; c2 < 64; ++c2) {
    float2 v = p[(size_t)c2 * BATCH * 256];
    acc.x += v.x; acc.y += v.y;
  }
  ((float2*)ctx)[b * 256 + t] = acc;
}

// Fallback ctx (small ws): atomicAdd into zeroed ctx, reads attn [s][b].
__global__ __launch_bounds__(256) void ctx_atomic_kernel(
    const float* __restrict__ src, const float* __restrict__ attn_g,
    float* __restrict__ ctx) {
  __shared__ float a_lds[128];
  const int s0 = blockIdx.x * 128, b = blockIdx.y, t = threadIdx.x;
  if (t < 128) a_lds[t] = attn_g[(s0 + t) * BATCH + b];
  __syncthreads();
  const int f4i = t & 127;
  const int sh = t >> 7;
  const float4* base =
      (const float4*)src + ((size_t)(s0 + sh * 64) * BATCH + b) * 128 + f4i;
  float4 acc = {0.f, 0.f, 0.f, 0.f};
#pragma unroll 8
  for (int i = 0; i < 64; ++i) {
    const float a = a_lds[sh * 64 + i];
    float4 v = base[(size_t)i * BATCH * 128];
    acc.x += a * v.x; acc.y += a * v.y; acc.z += a * v.z; acc.w += a * v.w;
  }
  float* cp = ctx + b * DDIM + f4i * 4;
  atomicAdd(cp + 0, acc.x);
  atomicAdd(cp + 1, acc.y);
  atomicAdd(cp + 2, acc.z);
  atomicAdd(cp + 3, acc.w);
}

// ---------------------------------------------------------------------------
extern "C" void kernel_launch(void* const* d_in, const int* in_sizes, int n_in,
                              void* d_out, int out_size, void* d_ws, size_t ws_size,
                              hipStream_t stream) {
  const float* input = (const float*)d_in[0];
  const float* src = (const float*)d_in[1];
  const unsigned char* mask = (const unsigned char*)d_in[2];
  const float* W1 = (const float*)d_in[3];
  const float* b1 = (const float*)d_in[4];
  const float* W2 = (const float*)d_in[5];
  // d_in[6] = b2: omitted (constant shift cancels in softmax)

  float* ctx = (float*)d_out;                  // [64,512]
  float* attn = (float*)d_out + BATCH * DDIM;  // [2048,64]

  // ws layout
  unsigned short* W1b = (unsigned short*)d_ws;                        // 512 KB
  float* uprime = (float*)((char*)d_ws + 512 * 1024);                 // 128 KB
  float* scores_t = (float*)((char*)d_ws + 640 * 1024);               // 512 KB
  float* attn_t = (float*)((char*)d_ws + 1152 * 1024);                // 512 KB
  float* partial = (float*)((char*)d_ws + 1664 * 1024);               // 8 MB
  const size_t NEED_ATTN_T = 1664 * 1024;
  const size_t NEED_PARTIAL = 1664 * 1024 + (size_t)64 * BATCH * DDIM * 4;
  const int have_attn_t = ws_size >= NEED_ATTN_T;
  const int have_partial = ws_size >= NEED_PARTIAL;

  prep_kernel<<<512, 256, 0, stream>>>(W1, b1, input, W1b, uprime);
  scores_kernel<<<S_LEN / 2, 512, 0, stream>>>(src, W1b, uprime, W2, scores_t);
  softmax_kernel<<<BATCH, 256, 0, stream>>>(scores_t, mask, attn, attn_t,
                                            have_attn_t && have_partial);
  if (have_partial) {
    ctx_partial_kernel<<<dim3(32, BATCH), 256, 0, stream>>>(src, attn_t, partial);
    ctx_reduce_kernel<<<BATCH, 256, 0, stream>>>(partial, ctx);
  } else {
    hipMemsetAsync(ctx, 0, BATCH * DDIM * sizeof(float), stream);
    ctx_atomic_kernel<<<dim3(16, BATCH), 256, 0, stream>>>(src, attn, ctx);
  }
}

// Round 2
// 502.669 us; speedup vs baseline: 1.0060x; 1.0060x over previous
//
#include <hip/hip_runtime.h>
#include <hip/hip_bf16.h>
#include <math.h>

// Problem constants (S, B, D_IN, D_SRC, D_ALIGN = 2048, 64, 512, 512, 512)
#define S_LEN 2048
#define BATCH 64
#define DDIM 512

typedef __attribute__((ext_vector_type(8))) short bf16x8;
typedef __attribute__((ext_vector_type(4))) float f32x4;
typedef __attribute__((ext_vector_type(4))) unsigned int u32x4;

__device__ __forceinline__ unsigned short f2bf(float f) {
  unsigned int u = __float_as_uint(f);
  u += 0x7fffu + ((u >> 16) & 1u);
  return (unsigned short)(u >> 16);
}

__device__ __forceinline__ float tanh_fast(float x) {
  // tanh(x) = 1 - 2/(exp2(2*log2e*x)+1)
  float e = __builtin_amdgcn_exp2f(x * 2.88539008177793f);
  return 1.0f - 2.0f * __builtin_amdgcn_rcpf(e + 1.0f);
}

// pack two f32 into bf16x2 (lo=a, hi=b), round-half-up (matches prior kernel)
__device__ __forceinline__ unsigned pkbf(float a, float b) {
  unsigned ua = __float_as_uint(a) + 0x8000u;
  unsigned ub = __float_as_uint(b) + 0x8000u;
  return __builtin_amdgcn_perm(ub, ua, 0x07060302u);
}

// ---------------------------------------------------------------------------
// prep: W1bT[kc][n][e] = bf16(W1[n][512 + kc*8 + e])  (k-chunk-major so scores
// can load B fragments straight from L2, coalesced 256B per 16-lane group);
// uprime[b][a] = b1[a] + W1[a,:512].input[b]
// ---------------------------------------------------------------------------
__global__ __launch_bounds__(256) void prep_kernel(
    const float* __restrict__ W1, const float* __restrict__ b1,
    const float* __restrict__ input, unsigned short* __restrict__ W1bT,
    float* __restrict__ uprime) {
  __shared__ float w1row[1024];
  const int a = blockIdx.x;
  const int t = threadIdx.x;
  float4 v = *(const float4*)(W1 + a * 1024 + t * 4);
  *(float4*)(w1row + t * 4) = v;
  if (t >= 128) {
    ushort4 u;
    u.x = f2bf(v.x); u.y = f2bf(v.y); u.z = f2bf(v.z); u.w = f2bf(v.w);
    const int d = t * 4 - 512;       // 0..508 step 4
    const int kc = d >> 3;           // k-chunk 0..63
    const int e = d & 7;             // 0 or 4
    *(ushort4*)(W1bT + ((size_t)kc * 512 + a) * 8 + e) = u;
  }
  __syncthreads();
  if (t < BATCH) {
    const float4* inp = (const float4*)(input + t * 512);
    const float4* wr = (const float4*)w1row;
    float acc = b1[a];
#pragma unroll 4
    for (int d = 0; d < 128; ++d) {
      float4 x = inp[d], w = wr[d];
      acc += x.x * w.x + x.y * w.y + x.z * w.z + x.w * w.w;
    }
    uprime[t * 512 + a] = acc;  // [b][a]
  }
}

// ---------------------------------------------------------------------------
// scores v6: BM=128 (2 s per block, grid 1024), 512 thr / 8 waves, wave w owns
// output cols w*64..w*64+63 -> acc[8][4].
// B: NO LDS — fragments loaded global->VGPR from W1bT (512KB, L2-resident).
// A: double-buffered LDS (2x16KB only). Per K-step: issue A-next global loads,
// load B regs for this step, compute (ds_read A + 64 MFMA), convert+ds_write
// A-next into other buffer, ONE barrier. Pre-barrier vmcnt/lgkm drain is ~free
// (everything already consumed). XOR-chunk swizzle on A as in v5 (verified).
// LDS 32.5KB, VGPR ~225 -> 2 blocks/CU, overlap across blocks.
// Epilogue: tanh + W2 dot, LDS reduce, write scores_t[b][s] (transposed).
// ---------------------------------------------------------------------------
__global__ __launch_bounds__(512, 2) void scores_kernel(
    const float* __restrict__ src, const unsigned short* __restrict__ W1bT,
    const float* __restrict__ uprime, const float* __restrict__ W2,
    float* __restrict__ scores_t) {
  __shared__ unsigned short A_sm[2][128 * 64];  // 2 x 16 KB
  __shared__ float s_lds[128];

  const int t = threadIdx.x;
  const int sblk = blockIdx.x;  // 2 s per block
  const int w = t >> 6;         // wave 0..7 (uniform)
  const int lane = t & 63;
  const int quad = lane >> 4;
  const int l15 = lane & 15;

  if (t < 128) s_lds[t] = 0.f;

  f32x4 acc[8][4];
#pragma unroll
  for (int i = 0; i < 8; ++i)
#pragma unroll
    for (int j = 0; j < 4; ++j) acc[i][j] = (f32x4){0.f, 0.f, 0.f, 0.f};

  // A staging: thread t -> row ar=t>>2, quarter aq=t&3 (16 f32 = 2 chunks).
  const int ar = t >> 2, aq = t & 3;
  const float* gA = src + (size_t)(sblk * 128) * DDIM + ar * DDIM + aq * 16;
  const int p0 = (2 * aq) ^ (ar & 7);  // phys chunks for logical 2aq, 2aq+1
  const int p1 = (2 * aq + 1) ^ (ar & 7);
  const int ldsA0 = ar * 64 + p0 * 8;
  const int ldsA1 = ar * 64 + p1 * 8;

  // B fragment base column for this lane (+ j*16 per fragment)
  const int ncol = w * 64 + l15;

  // ---- prologue: stage A tile 0 into buf 0 ----
  {
    float4 as0 = ((const float4*)gA)[0];
    float4 as1 = ((const float4*)gA)[1];
    float4 as2 = ((const float4*)gA)[2];
    float4 as3 = ((const float4*)gA)[3];
    u32x4 o0, o1;
    o0.x = pkbf(as0.x, as0.y); o0.y = pkbf(as0.z, as0.w);
    o0.z = pkbf(as1.x, as1.y); o0.w = pkbf(as1.z, as1.w);
    o1.x = pkbf(as2.x, as2.y); o1.y = pkbf(as2.z, as2.w);
    o1.z = pkbf(as3.x, as3.y); o1.w = pkbf(as3.z, as3.w);
    *(u32x4*)(A_sm[0] + ldsA0) = o0;
    *(u32x4*)(A_sm[0] + ldsA1) = o1;
  }
  __syncthreads();

  // ---- main loop: 8 K-steps of 64 ----
  for (int kt = 0; kt < 8; ++kt) {
    const int cur = kt & 1;
    const bool pf = kt < 7;
    float4 as0, as1, as2, as3;
    if (pf) {  // issue next A-tile loads first (HBM latency hides under compute)
      const float4* gAn = (const float4*)(gA + (kt + 1) * 64);
      as0 = gAn[0]; as1 = gAn[1]; as2 = gAn[2]; as3 = gAn[3];
    }

    // B fragments for this K-step: straight from L2 (W1bT), no LDS.
    bf16x8 bb[2][4];
#pragma unroll
    for (int ks = 0; ks < 2; ++ks)
#pragma unroll
      for (int j = 0; j < 4; ++j) {
        const int kc = kt * 8 + ks * 4 + quad;
        bb[ks][j] =
            *(const bf16x8*)(W1bT + ((size_t)kc * 512 + ncol + j * 16) * 8);
      }

    const unsigned short* Ac = A_sm[cur];
#pragma unroll
    for (int ks = 0; ks < 2; ++ks) {
      const int c = ks * 4 + quad;  // logical 16B chunk within BK=64
      bf16x8 af[8];
#pragma unroll
      for (int i = 0; i < 8; ++i) {
        const int r = i * 16 + l15;
        af[i] = *(const bf16x8*)(Ac + r * 64 + ((c ^ (r & 7)) << 3));
      }
#pragma unroll
      for (int i = 0; i < 8; ++i)
#pragma unroll
        for (int j = 0; j < 4; ++j)
          acc[i][j] = __builtin_amdgcn_mfma_f32_16x16x32_bf16(af[i], bb[ks][j],
                                                              acc[i][j], 0, 0, 0);
    }

    if (pf) {  // convert + write next A tile into the other buffer
      u32x4 o0, o1;
      o0.x = pkbf(as0.x, as0.y); o0.y = pkbf(as0.z, as0.w);
      o0.z = pkbf(as1.x, as1.y); o0.w = pkbf(as1.z, as1.w);
      o1.x = pkbf(as2.x, as2.y); o1.y = pkbf(as2.z, as2.w);
      o1.z = pkbf(as3.x, as3.y); o1.w = pkbf(as3.z, as3.w);
      *(u32x4*)(A_sm[cur ^ 1] + ldsA0) = o0;
      *(u32x4*)(A_sm[cur ^ 1] + ldsA1) = o1;
    }
    __syncthreads();  // A_sm[cur^1] ready for next step; drain is cheap here
  }

  // ---- epilogue: tanh + W2 partial dot over this wave's 64 cols ----
  float w2r[4];
#pragma unroll
  for (int j = 0; j < 4; ++j) w2r[j] = W2[w * 64 + j * 16 + l15];

#pragma unroll
  for (int i = 0; i < 8; ++i) {
#pragma unroll
    for (int r = 0; r < 4; ++r) {
      const int row = i * 16 + quad * 4 + r;  // 0..127
      const int b = row & 63;
      const int sl = row >> 6;
      const float* up = uprime + b * 512 + w * 64 + l15;
      float sp = 0.f;
#pragma unroll
      for (int j = 0; j < 4; ++j)
        sp += w2r[j] * tanh_fast(acc[i][j][r] + up[j * 16]);
      sp += __shfl_xor(sp, 1);
      sp += __shfl_xor(sp, 2);
      sp += __shfl_xor(sp, 4);
      sp += __shfl_xor(sp, 8);
      if (l15 == 0) atomicAdd(&s_lds[sl * 64 + b], sp);
    }
  }
  __syncthreads();
  if (t < 128)  // transposed [b][s]
    scores_t[(t & 63) * S_LEN + sblk * 2 + (t >> 6)] = s_lds[t];
}

// ---------------------------------------------------------------------------
// softmax over s per b; reads contiguous scores_t[b][s]. Writes attn[s][b]
// (output) and optionally attn_t[b][s] (ws, contiguous for ctx).
// ---------------------------------------------------------------------------
__global__ __launch_bounds__(256) void softmax_kernel(
    const float* __restrict__ scores_t, const unsigned char* __restrict__ mask,
    float* __restrict__ attn_g, float* __restrict__ attn_t, int write_t) {
  __shared__ float red[256];
  const int b = blockIdx.x, t = threadIdx.x;
  float m = -__builtin_inff();
  float sc[8];
#pragma unroll
  for (int c = 0; c < 8; ++c) {
    const int s = t + c * 256;
    sc[c] = mask[s * BATCH + b] ? -__builtin_inff() : scores_t[b * S_LEN + s];
    m = fmaxf(m, sc[c]);
  }
  red[t] = m;
  __syncthreads();
  for (int off = 128; off; off >>= 1) {
    if (t < off) red[t] = fmaxf(red[t], red[t + off]);
    __syncthreads();
  }
  m = red[0];
  __syncthreads();
  float sum = 0.f;
#pragma unroll
  for (int c = 0; c < 8; ++c) sum += __expf(sc[c] - m);
  red[t] = sum;
  __syncthreads();
  for (int off = 128; off; off >>= 1) {
    if (t < off) red[t] += red[t + off];
    __syncthreads();
  }
  const float inv = 1.f / red[0];
#pragma unroll
  for (int c = 0; c < 8; ++c) {
    const int s = t + c * 256;
    const float p = __expf(sc[c] - m) * inv;
    attn_g[s * BATCH + b] = p;
    if (write_t) attn_t[b * S_LEN + s] = p;
  }
}

// ---------------------------------------------------------------------------
// ctx two-stage (no atomics). Stage 1: grid (32 s-chunks, 64 b), each block
// computes two 32-s half-partials (float4 stores, coalesced).
// ---------------------------------------------------------------------------
__global__ __launch_bounds__(256) void ctx_partial_kernel(
    const float* __restrict__ src, const float* __restrict__ attn_t,
    float* __restrict__ partial) {
  __shared__ float a_lds[64];
  const int c = blockIdx.x;  // 0..31
  const int b = blockIdx.y;  // 0..63
  const int t = threadIdx.x;
  if (t < 64) a_lds[t] = attn_t[b * S_LEN + c * 64 + t];
  __syncthreads();
  const int f4i = t & 127;
  const int sh = t >> 7;
  const float4* base =
      (const float4*)src + ((size_t)(c * 64 + sh * 32) * BATCH + b) * 128 + f4i;
  float4 acc = {0.f, 0.f, 0.f, 0.f};
#pragma unroll 8
  for (int i = 0; i < 32; ++i) {
    const float a = a_lds[sh * 32 + i];
    float4 v = base[(size_t)i * BATCH * 128];
    acc.x += a * v.x; acc.y += a * v.y; acc.z += a * v.z; acc.w += a * v.w;
  }
  ((float4*)partial)[((size_t)(c * 2 + sh) * BATCH + b) * 128 + f4i] = acc;
}

// Stage 2: ctx[b][d] = sum over 64 half-partials. grid 64, 256 thr (float2/thr).
__global__ __launch_bounds__(256) void ctx_reduce_kernel(
    const float* __restrict__ partial, float* __restrict__ ctx) {
  const int b = blockIdx.x, t = threadIdx.x;
  const float2* p = (const float2*)partial + (size_t)b * 256 + t;
  float2 acc = {0.f, 0.f};
#pragma unroll 8
  for (int c2 = 0; c2 < 64; ++c2) {
    float2 v = p[(size_t)c2 * BATCH * 256];
    acc.x += v.x; acc.y += v.y;
  }
  ((float2*)ctx)[b * 256 + t] = acc;
}

// Fallback ctx (small ws): atomicAdd into zeroed ctx, reads attn [s][b].
__global__ __launch_bounds__(256) void ctx_atomic_kernel(
    const float* __restrict__ src, const float* __restrict__ attn_g,
    float* __restrict__ ctx) {
  __shared__ float a_lds[128];
  const int s0 = blockIdx.x * 128, b = blockIdx.y, t = threadIdx.x;
  if (t < 128) a_lds[t] = attn_g[(s0 + t) * BATCH + b];
  __syncthreads();
  const int f4i = t & 127;
  const int sh = t >> 7;
  const float4* base =
      (const float4*)src + ((size_t)(s0 + sh * 64) * BATCH + b) * 128 + f4i;
  float4 acc = {0.f, 0.f, 0.f, 0.f};
#pragma unroll 8
  for (int i = 0; i < 64; ++i) {
    const float a = a_lds[sh * 64 + i];
    float4 v = base[(size_t)i * BATCH * 128];
    acc.x += a * v.x; acc.y += a * v.y; acc.z += a * v.z; acc.w += a * v.w;
  }
  float* cp = ctx + b * DDIM + f4i * 4;
  atomicAdd(cp + 0, acc.x);
  atomicAdd(cp + 1, acc.y);
  atomicAdd(cp + 2, acc.z);
  atomicAdd(cp + 3, acc.w);
}

// ---------------------------------------------------------------------------
extern "C" void kernel_launch(void* const* d_in, const int* in_sizes, int n_in,
                              void* d_out, int out_size, void* d_ws, size_t ws_size,
                              hipStream_t stream) {
  const float* input = (const float*)d_in[0];
  const float* src = (const float*)d_in[1];
  const unsigned char* mask = (const unsigned char*)d_in[2];
  const float* W1 = (const float*)d_in[3];
  const float* b1 = (const float*)d_in[4];
  const float* W2 = (const float*)d_in[5];
  // d_in[6] = b2: omitted (constant shift cancels in softmax)

  float* ctx = (float*)d_out;                  // [64,512]
  float* attn = (float*)d_out + BATCH * DDIM;  // [2048,64]

  // ws layout
  unsigned short* W1bT = (unsigned short*)d_ws;                       // 512 KB
  float* uprime = (float*)((char*)d_ws + 512 * 1024);                 // 128 KB
  float* scores_t = (float*)((char*)d_ws + 640 * 1024);               // 512 KB
  float* attn_t = (float*)((char*)d_ws + 1152 * 1024);                // 512 KB
  float* partial = (float*)((char*)d_ws + 1664 * 1024);               // 8 MB
  const size_t NEED_ATTN_T = 1664 * 1024;
  const size_t NEED_PARTIAL = 1664 * 1024 + (size_t)64 * BATCH * DDIM * 4;
  const int have_attn_t = ws_size >= NEED_ATTN_T;
  const int have_partial = ws_size >= NEED_PARTIAL;

  prep_kernel<<<512, 256, 0, stream>>>(W1, b1, input, W1bT, uprime);
  scores_kernel<<<S_LEN / 2, 512, 0, stream>>>(src, W1bT, uprime, W2, scores_t);
  softmax_kernel<<<BATCH, 256, 0, stream>>>(scores_t, mask, attn, attn_t,
                                            have_attn_t && have_partial);
  if (have_partial) {
    ctx_partial_kernel<<<dim3(32, BATCH), 256, 0, stream>>>(src, attn_t, partial);
    ctx_reduce_kernel<<<BATCH, 256, 0, stream>>>(partial, ctx);
  } else {
    hipMemsetAsync(ctx, 0, BATCH * DDIM * sizeof(float), stream);
    ctx_atomic_kernel<<<dim3(16, BATCH), 256, 0, stream>>>(src, attn, ctx);
  }
}